// Round 1
// baseline (641.582 us; speedup 1.0000x reference)
//
#include <hip/hip_runtime.h>

// Problem: VQ embedding. z: (B=64, D=256, H=32, W=32) fp32; codebook: (K=1024, D=256) fp32.
// N = B*H*W = 65536 flattened vectors (n = b*1024 + h*32 + w), each picks argmin_k ||z_n - c_k||^2.
// Outputs (flat fp32 concat):
//   [0, 16777216)            quantized_st in (B,D,H,W) layout: z + (q - z)
//   [16777216, 16842752)     indices (B,1,H,W) as float
//   [16842752]               loss = 1.25 * sum((q - z)^2)

#define D_DIM 256
#define K_DIM 1024
#define HW    1024
#define N_VEC 65536
#define TN    64
#define TK    64
#define DC    32
#define ST_OFF   0
#define IDX_OFF  16777216
#define LOSS_OFF 16842752

// ---------------- Kernel 1: s_c[k] = sum_d codebook[k][d]^2 ----------------
__global__ __launch_bounds__(256) void vq_sumsq(const float* __restrict__ cb,
                                                float* __restrict__ sc) {
    const int t = threadIdx.x;
    const int row = blockIdx.x * 64 + (t >> 2);   // 64 rows per block, grid=16
    const int l4 = t & 3;
    float s = 0.f;
    #pragma unroll 8
    for (int i = 0; i < 64; i++) {
        float v = cb[(size_t)row * D_DIM + l4 + 4 * i];
        s = fmaf(v, v, s);
    }
    s += __shfl_xor(s, 1, 64);
    s += __shfl_xor(s, 2, 64);
    if (l4 == 0) sc[row] = s;
}

// ---------------- Kernel 2: fused distance-GEMM + argmin + outputs ----------------
__global__ __launch_bounds__(256) void vq_main(const float* __restrict__ z,
                                               const float* __restrict__ cb,
                                               const float* __restrict__ sc,
                                               float* __restrict__ out,
                                               float* __restrict__ partial) {
    __shared__ __align__(16) float z_s[DC][TN];    // [d_local][n_local]
    __shared__ __align__(16) float cb_s[DC][68];   // [d_local][k_local], stride 68 (16B-aligned rows, no bad banks)
    __shared__ int   bk_s[TN];
    __shared__ float red_s[4];

    const int t  = threadIdx.x;
    const int tx = t & 15;          // k quad
    const int ty = t >> 4;          // n quad (0..15)
    const int n0  = blockIdx.x * TN;
    const int b   = blockIdx.x >> 4;        // n0 / 1024
    const int hw0 = (blockIdx.x & 15) * TN;

    const int nl_ld = t & 63, dg_ld = t >> 6;   // z staging: lane -> n, wave -> d group
    const int dd_cb = t & 31, kg_cb = t >> 5;   // cb staging

    float best[4];
    int   bestk[4];
    #pragma unroll
    for (int i = 0; i < 4; i++) { best[i] = 3.4e38f; bestk[i] = 0; }

    for (int kt = 0; kt < K_DIM; kt += TK) {
        float acc[4][4];
        #pragma unroll
        for (int i = 0; i < 4; i++)
            #pragma unroll
            for (int j = 0; j < 4; j++) acc[i][j] = 0.f;

        for (int dc = 0; dc < D_DIM; dc += DC) {
            __syncthreads();   // protect previous iteration's reads
            // stage z chunk: 32 d x 64 n (coalesced: consecutive lanes -> consecutive hw)
            #pragma unroll
            for (int p = 0; p < 8; p++) {
                int dl = p * 4 + dg_ld;
                z_s[dl][nl_ld] = z[(size_t)(b * D_DIM + dc + dl) * HW + hw0 + nl_ld];
            }
            // stage cb chunk: 32 d x 64 k (coalesced: consecutive lanes -> consecutive d)
            #pragma unroll
            for (int p = 0; p < 8; p++) {
                int kloc = p * 8 + kg_cb;
                cb_s[dd_cb][kloc] = cb[(size_t)(kt + kloc) * D_DIM + dc + dd_cb];
            }
            __syncthreads();
            #pragma unroll
            for (int dd = 0; dd < DC; dd++) {
                float4 a4 = *(const float4*)&z_s[dd][ty * 4];
                float4 b4 = *(const float4*)&cb_s[dd][tx * 4];
                float av[4] = {a4.x, a4.y, a4.z, a4.w};
                float bv[4] = {b4.x, b4.y, b4.z, b4.w};
                #pragma unroll
                for (int i = 0; i < 4; i++)
                    #pragma unroll
                    for (int j = 0; j < 4; j++)
                        acc[i][j] = fmaf(av[i], bv[j], acc[i][j]);
            }
        }
        // score = ||c||^2 - 2 z.c  (||z||^2 is constant per n -> irrelevant for argmin)
        #pragma unroll
        for (int j = 0; j < 4; j++) {
            int k = kt + tx * 4 + j;
            float svk = sc[k];
            #pragma unroll
            for (int i = 0; i < 4; i++) {
                float v = svk - 2.0f * acc[i][j];
                if (v < best[i]) { best[i] = v; bestk[i] = k; }  // k ascends in-thread: strict < keeps first
            }
        }
    }

    // reduce argmin across the 16 tx lanes sharing each n row (first-index tie-break)
    #pragma unroll
    for (int i = 0; i < 4; i++) {
        float v = best[i];
        int   k = bestk[i];
        #pragma unroll
        for (int off = 1; off < 16; off <<= 1) {
            float vo = __shfl_xor(v, off, 64);
            int   ko = __shfl_xor(k, off, 64);
            if (vo < v || (vo == v && ko < k)) { v = vo; k = ko; }
        }
        if (tx == 0) bk_s[ty * 4 + i] = k;
    }
    __syncthreads();

    // indices output (as float)
    if (t < TN) out[IDX_OFF + n0 + t] = (float)bk_s[t];

    // quantized_st + loss partial
    float lsum = 0.f;
    const int nl = t & 63, dg = t >> 6;
    const int myk = bk_s[nl];
    #pragma unroll 4
    for (int p = 0; p < 64; p++) {
        int d = p * 4 + dg;
        size_t gi = (size_t)(b * D_DIM + d) * HW + hw0 + nl;
        float zv = z[gi];
        float qv = cb[(size_t)myk * D_DIM + d];
        float df = qv - zv;
        out[ST_OFF + gi] = zv + df;           // z + (q - z), matches reference formula
        lsum = fmaf(df, df, lsum);
    }
    lsum *= 1.25f;   // 0.25*commit + 1.0*embed, both sum((q-z)^2)
    #pragma unroll
    for (int off = 1; off < 64; off <<= 1) lsum += __shfl_xor(lsum, off, 64);
    if ((t & 63) == 0) red_s[t >> 6] = lsum;
    __syncthreads();
    if (t == 0) partial[blockIdx.x] = (red_s[0] + red_s[1]) + (red_s[2] + red_s[3]);
}

// ---------------- Kernel 3: loss reduction (deterministic, no atomics) ----------------
__global__ __launch_bounds__(256) void vq_loss_reduce(const float* __restrict__ partial,
                                                      float* __restrict__ out) {
    __shared__ float r_s[4];
    const int t = threadIdx.x;
    float s = (partial[t] + partial[t + 256]) + (partial[t + 512] + partial[t + 768]);
    #pragma unroll
    for (int off = 1; off < 64; off <<= 1) s += __shfl_xor(s, off, 64);
    if ((t & 63) == 0) r_s[t >> 6] = s;
    __syncthreads();
    if (t == 0) out[LOSS_OFF] = (r_s[0] + r_s[1]) + (r_s[2] + r_s[3]);
}

extern "C" void kernel_launch(void* const* d_in, const int* in_sizes, int n_in,
                              void* d_out, int out_size, void* d_ws, size_t ws_size,
                              hipStream_t stream) {
    const float* z  = (const float*)d_in[0];   // 16777216 elems
    const float* cb = (const float*)d_in[1];   // 262144 elems
    float* out = (float*)d_out;
    float* sc      = (float*)d_ws;             // 1024 floats
    float* partial = sc + K_DIM;               // 1024 floats

    vq_sumsq<<<16, 256, 0, stream>>>(cb, sc);
    vq_main<<<N_VEC / TN, 256, 0, stream>>>(z, cb, sc, out, partial);
    vq_loss_reduce<<<1, 256, 0, stream>>>(partial, out);
}

// Round 2
// 214.426 us; speedup vs baseline: 2.9921x; 2.9921x over previous
//
#include <hip/hip_runtime.h>

// VQ embedding, bf16-MFMA version.
// z: (B=64, D=256, H=32, W=32) fp32; codebook: (K=1024, D=256) fp32.
// n = b*1024 + hw; argmin_k ||z_n - c_k||^2 = argmin_k (||c_k||^2 - 2 z.c_k).
// Outputs (flat fp32): st[16777216] = chosen codebook row (== z+(q-z)),
// indices[65536] as float, loss = 1.25 * sum((q-z)^2) = 1.25*(sum z^2 + sum best_score).

#define IDX_OFF  16777216
#define LOSS_OFF 16842752

typedef __bf16 bf16x8 __attribute__((ext_vector_type(8)));
typedef float  f32x4  __attribute__((ext_vector_type(4)));

// ---------------- Kernel 1: cb fp32 -> bf16 copy + row norms ----------------
__global__ __launch_bounds__(256) void vq_prep(const float* __restrict__ cb,
                                               __bf16* __restrict__ cbh,
                                               float* __restrict__ sc) {
    const int t = threadIdx.x;
    const int r = blockIdx.x * 64 + (t >> 2);
    const int d0 = (t & 3) * 64;
    const float* src = cb + (size_t)r * 256 + d0;
    __bf16* dst = cbh + (size_t)r * 256 + d0;
    float s = 0.f;
    #pragma unroll
    for (int p = 0; p < 8; p++) {
        float4 f0 = *(const float4*)(src + p * 8);
        float4 f1 = *(const float4*)(src + p * 8 + 4);
        s = fmaf(f0.x, f0.x, s); s = fmaf(f0.y, f0.y, s);
        s = fmaf(f0.z, f0.z, s); s = fmaf(f0.w, f0.w, s);
        s = fmaf(f1.x, f1.x, s); s = fmaf(f1.y, f1.y, s);
        s = fmaf(f1.z, f1.z, s); s = fmaf(f1.w, f1.w, s);
        bf16x8 v;
        v[0] = (__bf16)f0.x; v[1] = (__bf16)f0.y; v[2] = (__bf16)f0.z; v[3] = (__bf16)f0.w;
        v[4] = (__bf16)f1.x; v[5] = (__bf16)f1.y; v[6] = (__bf16)f1.z; v[7] = (__bf16)f1.w;
        *(bf16x8*)(dst + p * 8) = v;
    }
    s += __shfl_xor(s, 1, 64);
    s += __shfl_xor(s, 2, 64);
    if ((t & 3) == 0) sc[r] = s;
}

// ---------------- Kernel 2: MFMA distance-GEMM + argmin + outputs ----------------
// Block: 128 n-rows x all 1024 codes. 4 waves, each 64n x 64k (4x4 mfma subtiles).
// LDS: exactly 64 KB, one buffer, multi-purpose:
//   phase A: z tile [128 n][256 d] bf16, 16B-group XOR-swizzled (g' = g ^ (n&7))
//   phase B (z dead): argmin scratch (bv2/bk2/kf/red)
//   phase C: chosen-q tile [128 n][256 d] bf16, same swizzle, for coalesced st emit
__global__ __launch_bounds__(256, 2) void vq_mfma(const float* __restrict__ z,
                                                  const __bf16* __restrict__ cbh,
                                                  const float* __restrict__ sc,
                                                  float* __restrict__ out,
                                                  float* __restrict__ partial) {
    __shared__ __align__(16) __bf16 z_s[128 * 256];   // 65536 B

    const int t    = threadIdx.x;
    const int lane = t & 63;
    const int w    = t >> 6;
    const int m16  = lane & 15;
    const int q4   = lane >> 4;
    const int wn   = (w >> 1) * 64;   // wave row offset
    const int wk   = (w & 1) * 64;    // wave col offset
    const int blk  = blockIdx.x;
    const int b    = blk >> 3;
    const int hw0  = (blk & 7) << 7;
    const int n0   = blk << 7;

    // ---- phase A: stage z (fp32 global, coalesced) -> bf16 LDS [n][d]; sum z^2
    float lz = 0.f;
    {
        const int nl    = t & 127;
        const int dhalf = (t >> 7) << 7;   // 0 or 128
        const float* zp = z + (size_t)(b * 256 + dhalf) * 1024 + hw0 + nl;
        #pragma unroll
        for (int p = 0; p < 16; p++) {
            bf16x8 v;
            #pragma unroll
            for (int j = 0; j < 8; j++) {
                float f = zp[(size_t)(p * 8 + j) * 1024];
                lz = fmaf(f, f, lz);
                v[j] = (__bf16)f;
            }
            int gs = ((dhalf >> 3) + p) ^ (nl & 7);
            *(bf16x8*)&z_s[nl * 256 + gs * 8] = v;
        }
    }
    __syncthreads();

    // ---- GEMM + running argmin (no barriers in this loop)
    float bestv[16];
    int   bestk[16];
    #pragma unroll
    for (int i = 0; i < 16; i++) { bestv[i] = 3.4e38f; bestk[i] = 0; }

    const int arow = wn + m16;
    #pragma unroll 1
    for (int kt = 0; kt < 1024; kt += 128) {
        const __bf16* bp0 = cbh + (size_t)(kt + wk + m16) * 256 + q4 * 8;
        f32x4 acc[4][4];
        #pragma unroll
        for (int i = 0; i < 4; i++)
            #pragma unroll
            for (int j = 0; j < 4; j++) acc[i][j] = (f32x4){0.f, 0.f, 0.f, 0.f};

        #pragma unroll
        for (int dc = 0; dc < 256; dc += 32) {
            bf16x8 a[4], bb[4];
            const int gs = ((dc >> 3) + q4) ^ (m16 & 7);
            #pragma unroll
            for (int i = 0; i < 4; i++)
                a[i] = *(const bf16x8*)&z_s[(arow + i * 16) * 256 + gs * 8];
            #pragma unroll
            for (int j = 0; j < 4; j++)
                bb[j] = *(const bf16x8*)(bp0 + (size_t)j * 16 * 256 + dc);
            #pragma unroll
            for (int i = 0; i < 4; i++)
                #pragma unroll
                for (int j = 0; j < 4; j++)
                    acc[i][j] = __builtin_amdgcn_mfma_f32_16x16x32_bf16(a[i], bb[j], acc[i][j], 0, 0, 0);
        }
        // score = ||c||^2 - 2 z.c ; fold into running argmin (k ascending in-thread)
        #pragma unroll
        for (int j = 0; j < 4; j++) {
            int kc = kt + wk + j * 16 + m16;
            float sck = sc[kc];
            #pragma unroll
            for (int i = 0; i < 4; i++)
                #pragma unroll
                for (int r = 0; r < 4; r++) {
                    float v2 = fmaf(-2.f, acc[i][j][r], sck);
                    int pos = i * 4 + r;
                    if (v2 < bestv[pos]) { bestv[pos] = v2; bestk[pos] = kc; }
                }
        }
    }

    // ---- intra-wave argmin across the 16 col-lanes (first-index tie-break)
    #pragma unroll
    for (int pos = 0; pos < 16; pos++) {
        float v = bestv[pos]; int k = bestk[pos];
        #pragma unroll
        for (int off = 1; off < 16; off <<= 1) {
            float vo = __shfl_xor(v, off, 64);
            int   ko = __shfl_xor(k, off, 64);
            if (vo < v || (vo == v && ko < k)) { v = vo; k = ko; }
        }
        bestv[pos] = v; bestk[pos] = k;
    }
    __syncthreads();              // all z_s reads done -> z_s becomes scratch

    // ---- phase B: cross-wave combine in recycled z_s
    float* fs = (float*)z_s;      // fs[0..256): bv2[slot][row]; int[256..512): bk2;
    int*   is = (int*)z_s;        // fs[512..640): chosen k as float; fs[640..644): red
    if (m16 == 0) {
        #pragma unroll
        for (int pos = 0; pos < 16; pos++) {
            int i = pos >> 2, r = pos & 3;
            int row = wn + i * 16 + q4 * 4 + r;
            fs[(w & 1) * 128 + row] = bestv[pos];
            is[256 + (w & 1) * 128 + row] = bestk[pos];
        }
    }
    __syncthreads();
    if (t < 128) {
        float v0 = fs[t], v1 = fs[128 + t];
        int   k0 = is[256 + t], k1 = is[256 + 128 + t];
        int   kf = (v1 < v0) ? k1 : k0;            // tie -> k0 (smaller k)
        float vf = (v1 < v0) ? v1 : v0;
        fs[512 + t] = (float)kf;
        out[IDX_OFF + n0 + t] = (float)kf;
        lz += vf;                                   // loss += best score for this row
    }
    // block loss reduce: sum(z^2) + sum(best score)
    {
        float s = lz;
        #pragma unroll
        for (int off = 1; off < 64; off <<= 1) s += __shfl_xor(s, off, 64);
        if (lane == 0) fs[640 + w] = s;
    }
    __syncthreads();
    if (t == 0) partial[blk] = (fs[640] + fs[641]) + (fs[642] + fs[643]);

    // ---- phase C: stage chosen codebook rows into z_s, then coalesced emit
    const int qrow = t >> 1;
    const int qoff = (t & 1) * 128;
    const int myk  = (int)fs[512 + qrow];
    __syncthreads();              // everyone has read kf; safe to overwrite z_s
    {
        const __bf16* qp = cbh + (size_t)myk * 256 + qoff;
        #pragma unroll
        for (int p = 0; p < 16; p++) {
            bf16x8 v = *(const bf16x8*)(qp + p * 8);
            int gs = ((qoff >> 3) + p) ^ (qrow & 7);
            *(bf16x8*)&z_s[qrow * 256 + gs * 8] = v;
        }
    }
    __syncthreads();
    {
        const int nl    = t & 127;
        const int dhalf = (t >> 7) << 7;
        float* op = out + (size_t)(b * 256 + dhalf) * 1024 + hw0 + nl;
        #pragma unroll
        for (int p = 0; p < 16; p++) {
            int gs = ((dhalf >> 3) + p) ^ (nl & 7);
            bf16x8 v = *(const bf16x8*)&z_s[nl * 256 + gs * 8];
            #pragma unroll
            for (int j = 0; j < 8; j++)
                op[(size_t)(p * 8 + j) * 1024] = (float)v[j];
        }
    }
}

// ---------------- Kernel 3: loss reduction over 512 block partials ----------------
__global__ __launch_bounds__(256) void vq_loss_reduce(const float* __restrict__ partial,
                                                      float* __restrict__ out) {
    __shared__ float r_s[4];
    const int t = threadIdx.x;
    float s = partial[t] + partial[t + 256];
    #pragma unroll
    for (int off = 1; off < 64; off <<= 1) s += __shfl_xor(s, off, 64);
    if ((t & 63) == 0) r_s[t >> 6] = s;
    __syncthreads();
    if (t == 0) out[LOSS_OFF] = 1.25f * ((r_s[0] + r_s[1]) + (r_s[2] + r_s[3]));
}

extern "C" void kernel_launch(void* const* d_in, const int* in_sizes, int n_in,
                              void* d_out, int out_size, void* d_ws, size_t ws_size,
                              hipStream_t stream) {
    const float* z  = (const float*)d_in[0];   // 16777216
    const float* cb = (const float*)d_in[1];   // 262144
    float* out = (float*)d_out;

    float*  sc      = (float*)d_ws;                        // 1024 f
    float*  partial = sc + 1024;                           // 512 f
    __bf16* cbh     = (__bf16*)((char*)d_ws + 8192);       // 512 KB

    vq_prep<<<16, 256, 0, stream>>>(cb, cbh, sc);
    vq_mfma<<<512, 256, 0, stream>>>(z, cbh, sc, out, partial);
    vq_loss_reduce<<<1, 256, 0, stream>>>(partial, out);
}